// Round 6
// baseline (126.519 us; speedup 1.0000x reference)
//
#include <hip/hip_runtime.h>

// QuantizedConv2d int8 3x3, N=64, Cin=Cout=128, 56x56, pad=1 (value = input zp),
// int32 accum, per-channel requant. Harness widens integer arrays to int32
// (inputs AND output buffer).
//
// R6: three kernels.
//  1) pack_w2: weights -> swizzled int8 [36 steps][4KB] (as R5).
//  2) repack_x: x int32 NCHW -> xp int8 NHWC PADDED [64][58][58][128] in d_ws
//     (halo rows/cols pre-filled with input zp). 27.56 MB.
//  3) conv_mfma: implicit GEMM v_mfma_i32_32x32x32_i8 (D=[cout][px], coalesced
//     stores). x-tile staged via linear global_load_lds with pre-swizzled
//     per-lane SOURCE addresses (LDS dest linear, read-side XOR swizzle
//     preserved); B double-buffered via global_load_lds, 1 barrier per 8KB
//     unit. Compute/epilogue identical to R5 (verified).

#define CIN  128
#define COUT 128
#define HW   56
#define NPIX (HW * HW)
#define ROWS  4
#define QCOLS 58
#define XROW  (QCOLS * CIN)          // 7424 B per padded row
#define XP_OFF 147456                // xp starts after wp2 in d_ws
#define XP_ROWS (64 * QCOLS)         // 3712

typedef int v4i  __attribute__((ext_vector_type(4)));
typedef int v16i __attribute__((ext_vector_type(16)));

__device__ __forceinline__ void gl16(const void* g, void* l) {
    __builtin_amdgcn_global_load_lds(
        (const __attribute__((address_space(1))) unsigned*)g,
        (__attribute__((address_space(3))) unsigned*)l, 16, 0, 0);
}

// ---- pack weights, swizzled (unchanged from R5) ----
// step = t*4+cb; in-chunk granule g = cout*2+(dw>>2); gs = g ^ ((g>>3)&7);
// chunk dword = gs*4 + (dw&3). byte b of dword dw -> ci = cb*32+dw*4+b, tap t.
__global__ __launch_bounds__(256) void pack_w2(const int* __restrict__ w_g,
                                               unsigned* __restrict__ wp2) {
    int i = blockIdx.x * 256 + threadIdx.x;
    if (i >= 36 * 128 * 8) return;
    int dw   = i & 7;
    int cout = (i >> 3) & 127;
    int step = i >> 10;
    int t  = step >> 2;
    int cb = step & 3;
    unsigned d = 0;
#pragma unroll
    for (int b = 0; b < 4; ++b) {
        int ci = cb * 32 + dw * 4 + b;
        int v = w_g[(cout * CIN + ci) * 9 + t];
        d |= (unsigned)(v & 0xFF) << (8 * b);
    }
    int g  = (cout << 1) | (dw >> 2);
    int gs = g ^ ((g >> 3) & 7);
    wp2[step * 1024 + gs * 4 + (dw & 3)] = d;
}

// ---- repack x: NCHW int32 -> NHWC int8 padded, halo = zp ----
// block = (n, hp); row = 58 cols x 128 ci = 1856 dwords, dword d = wp*32+ci4.
__global__ __launch_bounds__(256) void repack_x(const int* __restrict__ x_g,
                                                unsigned char* __restrict__ xp,
                                                const int* __restrict__ zp_in_p) {
    const int blk = blockIdx.x;          // n*58 + hp
    const int n  = blk / QCOLS;
    const int hp = blk % QCOLS;
    const unsigned zpd = (unsigned)((*zp_in_p) & 0xFF) * 0x01010101u;
    unsigned* row = (unsigned*)(xp + (size_t)blk * XROW);

    if (hp == 0 || hp == QCOLS - 1) {
        for (int d = threadIdx.x; d < QCOLS * 32; d += 256) row[d] = zpd;
        return;
    }
    const int h = hp - 1;
    for (int d = threadIdx.x; d < QCOLS * 32; d += 256) {
        int wp  = d >> 5;
        int ci4 = d & 31;
        unsigned v = zpd;
        if (wp >= 1 && wp <= HW) {
            const int* xb = x_g + ((n * CIN + ci4 * 4) * HW + h) * HW + (wp - 1);
            v = (unsigned)(xb[0] & 0xFF) |
                ((unsigned)(xb[NPIX] & 0xFF) << 8) |
                ((unsigned)(xb[2 * NPIX] & 0xFF) << 16) |
                ((unsigned)(xb[3 * NPIX] & 0xFF) << 24);
        }
        row[d] = v;
    }
}

// ---- conv ----
__global__ __launch_bounds__(256, 2) void conv_mfma(
    const unsigned char* __restrict__ xp, const unsigned char* __restrict__ wp2b,
    const int* __restrict__ bias, const float* __restrict__ in_s,
    const float* __restrict__ w_s, const float* __restrict__ out_s,
    const int* __restrict__ zp_out_p, int* __restrict__ out) {
    __shared__ unsigned char xsb[45056];     // 44 x 1024B (348 rows used)
    __shared__ unsigned char Bb2[2][8192];   // B unit double buffer
    __shared__ float scs[COUT];
    __shared__ int   bis[COUT];

    const int n   = blockIdx.x / 14;
    const int ho0 = (blockIdx.x % 14) * ROWS;
    const int tid    = threadIdx.x;
    const int lane   = tid & 63;
    const int wave   = tid >> 6;
    const int lane31 = lane & 31;
    const int hi     = lane >> 5;
    const int hi4    = hi * 4;

    // ---- requant constants ----
    if (tid < COUT) {
        scs[tid] = ((*in_s) / (*out_s)) * w_s[tid];
        bis[tid] = bias[tid];
    }

    // ---- stage x window: 6 padded rows = 44544 contiguous bytes ----
    // LDS linear; source pre-swizzled so LDS slot (q, s') holds global granule
    // s'^(q&7) of row q  (q&7 == lane>>3 within each 8-row group).
    const unsigned char* win = xp + (size_t)(n * QCOLS + ho0) * XROW;
    const int qrel = lane >> 3;                       // row within 8-row group
    const int lof  = (qrel * 8 + ((lane & 7) ^ qrel)) * 16;
    for (int i = wave; i < 44; i += 4) {
        int off = i * 1024 + lof;
        if (i == 43 && qrel >= 4) off = lof & 0;      // clamp: rows 348+ unused
        gl16(win + off, xsb + i * 1024);
    }
    // ---- stage B unit 0 ----
    {
        const unsigned char* bs = wp2b + wave * 2048 + lane * 16;
        gl16(bs, &Bb2[0][wave * 2048]);
        gl16(bs + 1024, &Bb2[0][wave * 2048 + 1024]);
    }
    __syncthreads();

    // ---- per-wave geometry ----
    const unsigned* xs = (const unsigned*)xsb;
    int qb[2];
#pragma unroll
    for (int i = 0; i < 2; ++i) {
        int px = (wave * 2 + i) * 32 + lane31;
        if (px > ROWS * HW - 1) px = ROWS * HW - 1;   // wave3/i=1 clamp
        qb[i] = (px / HW) * QCOLS + (px % HW);
    }
    int boff[4];
#pragma unroll
    for (int nt = 0; nt < 4; ++nt) {
        int g = nt * 64 + lane31 * 2 + hi;
        boff[nt] = (g ^ ((g >> 3) & 7)) * 16;
    }

    v16i acc[2][4];
#pragma unroll
    for (int i = 0; i < 2; ++i)
#pragma unroll
        for (int j = 0; j < 4; ++j) acc[i][j] = (v16i)0;

    // ---- K loop: 18 units (tap t = u>>1, ci-halves), 8KB B per unit ----
#pragma unroll 1
    for (int u = 0; u < 18; ++u) {
        if (u < 17) {
            const unsigned char* bs = wp2b + (u + 1) * 8192 + wave * 2048 + lane * 16;
            unsigned char* bd = &Bb2[(u + 1) & 1][wave * 2048];
            gl16(bs, bd);
            gl16(bs + 1024, bd + 1024);
        }
        const int t  = u >> 1;
        const int dq = (t / 3) * QCOLS + (t % 3);
        const int q0 = qb[0] + dq, q1 = qb[1] + dq;
        const int s0 = (q0 & 7) << 2, s1 = (q1 & 7) << 2;
        const unsigned char* bb = Bb2[u & 1];
#pragma unroll
        for (int c = 0; c < 2; ++c) {
            const int cb = (u & 1) * 2 + c;
            v4i a0 = *(const v4i*)&xs[q0 * 32 + ((cb * 8 + hi4) ^ s0)];
            v4i a1 = *(const v4i*)&xs[q1 * 32 + ((cb * 8 + hi4) ^ s1)];
            const unsigned char* bc = bb + c * 4096;
            v4i b0 = *(const v4i*)(bc + boff[0]);
            v4i b1 = *(const v4i*)(bc + boff[1]);
            v4i b2 = *(const v4i*)(bc + boff[2]);
            v4i b3 = *(const v4i*)(bc + boff[3]);
            acc[0][0] = __builtin_amdgcn_mfma_i32_32x32x32_i8(b0, a0, acc[0][0], 0, 0, 0);
            acc[0][1] = __builtin_amdgcn_mfma_i32_32x32x32_i8(b1, a0, acc[0][1], 0, 0, 0);
            acc[0][2] = __builtin_amdgcn_mfma_i32_32x32x32_i8(b2, a0, acc[0][2], 0, 0, 0);
            acc[0][3] = __builtin_amdgcn_mfma_i32_32x32x32_i8(b3, a0, acc[0][3], 0, 0, 0);
            acc[1][0] = __builtin_amdgcn_mfma_i32_32x32x32_i8(b0, a1, acc[1][0], 0, 0, 0);
            acc[1][1] = __builtin_amdgcn_mfma_i32_32x32x32_i8(b1, a1, acc[1][1], 0, 0, 0);
            acc[1][2] = __builtin_amdgcn_mfma_i32_32x32x32_i8(b2, a1, acc[1][2], 0, 0, 0);
            acc[1][3] = __builtin_amdgcn_mfma_i32_32x32x32_i8(b3, a1, acc[1][3], 0, 0, 0);
        }
        __syncthreads();
    }

    // ---- epilogue: D row = cout-in-tile = (reg&3)+8*(reg>>2)+hi4, col = px ----
    const float zpo = (float)(*zp_out_p);
#pragma unroll
    for (int i = 0; i < 2; ++i) {
        const int px = (wave * 2 + i) * 32 + lane31;
        if (px < ROWS * HW) {
            int* ob = out + n * COUT * NPIX + ho0 * HW + px;   // + co*NPIX
#pragma unroll
            for (int nt = 0; nt < 4; ++nt) {
#pragma unroll
                for (int reg = 0; reg < 16; ++reg) {
                    int co = nt * 32 + (reg & 3) + 8 * (reg >> 2) + hi4;
                    float f = fmaf((float)(acc[i][nt][reg] + bis[co]), scs[co], zpo);
                    f = rintf(f);
                    f = fminf(fmaxf(f, -128.0f), 127.0f);
                    ob[co * NPIX] = (int)f;
                }
            }
        }
    }
}

extern "C" void kernel_launch(void* const* d_in, const int* in_sizes, int n_in,
                              void* d_out, int out_size, void* d_ws, size_t ws_size,
                              hipStream_t stream) {
    const int* x_g      = (const int*)d_in[0];
    const int* w_g      = (const int*)d_in[1];
    const int* bias     = (const int*)d_in[2];
    const float* in_s   = (const float*)d_in[3];
    const float* w_s    = (const float*)d_in[4];
    const float* out_s  = (const float*)d_in[5];
    const int* zp_in_p  = (const int*)d_in[6];
    const int* zp_out_p = (const int*)d_in[7];
    int* outp = (int*)d_out;
    unsigned* wp2 = (unsigned*)d_ws;                           // 147456 B
    unsigned char* xpp = (unsigned char*)d_ws + XP_OFF;        // 27,557,888 B

    pack_w2<<<(36 * 128 * 8 + 255) / 256, 256, 0, stream>>>(w_g, wp2);
    repack_x<<<XP_ROWS, 256, 0, stream>>>(x_g, xpp, zp_in_p);

    const int nblocks = 64 * (HW / ROWS);   // 896
    conv_mfma<<<nblocks, 256, 0, stream>>>(xpp, (const unsigned char*)wp2, bias,
                                           in_s, w_s, out_s, zp_out_p, outp);
}

// Round 7
// 85.808 us; speedup vs baseline: 1.4744x; 1.4744x over previous
//
#include <hip/hip_runtime.h>

// QuantizedConv2d int8 3x3, N=64, Cin=Cout=128, 56x56, pad=1 (value = input zp),
// int32 accum, per-channel requant. Harness widens integer arrays to int32
// (inputs AND output buffer).
//
// R7: R6 conv (unchanged, verified) + fast LDS-transpose repack_x.
//  1) pack_w2: weights -> swizzled int8 [36 steps][4KB].
//  2) repack_x: x int32 NCHW -> xp int8 NHWC PADDED [64][58][58][128] in d_ws.
//     Block=(n,hp). Read: dwordx4 along w within ci-plane (contiguous) -> LDS
//     [ci][w] stride-57. Pack: thread=out-dword packs 4 LDS bytes, coalesced
//     global write. Halo rows/cols = zp.
//  3) conv_mfma: implicit GEMM v_mfma_i32_32x32x32_i8, D=[cout][px], x staged
//     by linear global_load_lds with pre-swizzled source granules, B 8KB
//     double-buffered via global_load_lds, 1 barrier/unit.

#define CIN  128
#define COUT 128
#define HW   56
#define NPIX (HW * HW)
#define ROWS  4
#define QCOLS 58
#define XROW  (QCOLS * CIN)          // 7424 B per padded row
#define XP_OFF 147456                // xp starts after wp2 in d_ws
#define XP_ROWS (64 * QCOLS)         // 3712

typedef int v4i  __attribute__((ext_vector_type(4)));
typedef int v16i __attribute__((ext_vector_type(16)));

__device__ __forceinline__ void gl16(const void* g, void* l) {
    __builtin_amdgcn_global_load_lds(
        (const __attribute__((address_space(1))) unsigned*)g,
        (__attribute__((address_space(3))) unsigned*)l, 16, 0, 0);
}

// ---- pack weights, swizzled ----
// step = t*4+cb; in-chunk granule g = cout*2+(dw>>2); gs = g ^ ((g>>3)&7);
// chunk dword = gs*4 + (dw&3). byte b of dword dw -> ci = cb*32+dw*4+b, tap t.
__global__ __launch_bounds__(256) void pack_w2(const int* __restrict__ w_g,
                                               unsigned* __restrict__ wp2) {
    int i = blockIdx.x * 256 + threadIdx.x;
    if (i >= 36 * 128 * 8) return;
    int dw   = i & 7;
    int cout = (i >> 3) & 127;
    int step = i >> 10;
    int t  = step >> 2;
    int cb = step & 3;
    unsigned d = 0;
#pragma unroll
    for (int b = 0; b < 4; ++b) {
        int ci = cb * 32 + dw * 4 + b;
        int v = w_g[(cout * CIN + ci) * 9 + t];
        d |= (unsigned)(v & 0xFF) << (8 * b);
    }
    int g  = (cout << 1) | (dw >> 2);
    int gs = g ^ ((g >> 3) & 7);
    wp2[step * 1024 + gs * 4 + (dw & 3)] = d;
}

// ---- repack x: LDS transpose. block = (n, hp) ----
#define LSTR 57   // LDS row stride in dwords (odd -> spread banks)
__global__ __launch_bounds__(256) void repack_x(const int* __restrict__ x_g,
                                                unsigned char* __restrict__ xp,
                                                const int* __restrict__ zp_in_p) {
    __shared__ int lx[CIN * LSTR];       // 29184 B, [ci][w] int32 values
    const int blk = blockIdx.x;          // n*58 + hp
    const int n  = blk / QCOLS;
    const int hp = blk % QCOLS;
    const int tid = threadIdx.x;
    const unsigned zpd = (unsigned)((*zp_in_p) & 0xFF) * 0x01010101u;
    unsigned* row = (unsigned*)(xp + (size_t)blk * XROW);

    if (hp == 0 || hp == QCOLS - 1) {    // padding rows
#pragma unroll
        for (int it = 0; it < 8; ++it) {
            int d = it * 256 + tid;
            if (d < QCOLS * 32) row[d] = zpd;
        }
        return;
    }
    const int h = hp - 1;
    // ---- read phase: 128 ci x 14 dwordx4 along w (contiguous per ci) ----
    const int* xrow = x_g + (n * CIN * HW + h) * HW;   // + ci*NPIX + w
#pragma unroll
    for (int it = 0; it < 7; ++it) {
        int idx = it * 256 + tid;        // 0..1791
        int ci  = idx / 14;
        int w4  = (idx - ci * 14) * 4;
        v4i L = *(const v4i*)(xrow + ci * NPIX + w4);
        int* ld = &lx[ci * LSTR + w4];
        ld[0] = L[0]; ld[1] = L[1]; ld[2] = L[2]; ld[3] = L[3];
    }
    __syncthreads();
    // ---- pack phase: out dword d = wp*32 + ci4 ; bytes = ci4*4..+3, w=wp-1 ----
#pragma unroll
    for (int it = 0; it < 8; ++it) {
        int d = it * 256 + tid;
        if (d < QCOLS * 32) {
            int wp  = d >> 5;
            int ci4 = d & 31;
            unsigned v = zpd;
            if (wp >= 1 && wp <= HW) {
                const int* lb = &lx[ci4 * 4 * LSTR + (wp - 1)];
                v = (unsigned)(lb[0] & 0xFF) |
                    ((unsigned)(lb[LSTR] & 0xFF) << 8) |
                    ((unsigned)(lb[2 * LSTR] & 0xFF) << 16) |
                    ((unsigned)(lb[3 * LSTR] & 0xFF) << 24);
            }
            row[d] = v;
        }
    }
}

// ---- conv (unchanged from R6, verified) ----
__global__ __launch_bounds__(256, 2) void conv_mfma(
    const unsigned char* __restrict__ xp, const unsigned char* __restrict__ wp2b,
    const int* __restrict__ bias, const float* __restrict__ in_s,
    const float* __restrict__ w_s, const float* __restrict__ out_s,
    const int* __restrict__ zp_out_p, int* __restrict__ out) {
    __shared__ unsigned char xsb[45056];     // 44 x 1024B (348 rows used)
    __shared__ unsigned char Bb2[2][8192];   // B unit double buffer
    __shared__ float scs[COUT];
    __shared__ int   bis[COUT];

    const int n   = blockIdx.x / 14;
    const int ho0 = (blockIdx.x % 14) * ROWS;
    const int tid    = threadIdx.x;
    const int lane   = tid & 63;
    const int wave   = tid >> 6;
    const int lane31 = lane & 31;
    const int hi     = lane >> 5;
    const int hi4    = hi * 4;

    if (tid < COUT) {
        scs[tid] = ((*in_s) / (*out_s)) * w_s[tid];
        bis[tid] = bias[tid];
    }

    // ---- stage x window: 6 padded rows = 44544 contiguous bytes ----
    const unsigned char* win = xp + (size_t)(n * QCOLS + ho0) * XROW;
    const int qrel = lane >> 3;
    const int lof  = (qrel * 8 + ((lane & 7) ^ qrel)) * 16;
    for (int i = wave; i < 44; i += 4) {
        int off = i * 1024 + lof;
        if (i == 43 && qrel >= 4) off = lof & 0;
        gl16(win + off, xsb + i * 1024);
    }
    // ---- stage B unit 0 ----
    {
        const unsigned char* bs = wp2b + wave * 2048 + lane * 16;
        gl16(bs, &Bb2[0][wave * 2048]);
        gl16(bs + 1024, &Bb2[0][wave * 2048 + 1024]);
    }
    __syncthreads();

    const unsigned* xs = (const unsigned*)xsb;
    int qb[2];
#pragma unroll
    for (int i = 0; i < 2; ++i) {
        int px = (wave * 2 + i) * 32 + lane31;
        if (px > ROWS * HW - 1) px = ROWS * HW - 1;
        qb[i] = (px / HW) * QCOLS + (px % HW);
    }
    int boff[4];
#pragma unroll
    for (int nt = 0; nt < 4; ++nt) {
        int g = nt * 64 + lane31 * 2 + hi;
        boff[nt] = (g ^ ((g >> 3) & 7)) * 16;
    }

    v16i acc[2][4];
#pragma unroll
    for (int i = 0; i < 2; ++i)
#pragma unroll
        for (int j = 0; j < 4; ++j) acc[i][j] = (v16i)0;

#pragma unroll 1
    for (int u = 0; u < 18; ++u) {
        if (u < 17) {
            const unsigned char* bs = wp2b + (u + 1) * 8192 + wave * 2048 + lane * 16;
            unsigned char* bd = &Bb2[(u + 1) & 1][wave * 2048];
            gl16(bs, bd);
            gl16(bs + 1024, bd + 1024);
        }
        const int t  = u >> 1;
        const int dq = (t / 3) * QCOLS + (t % 3);
        const int q0 = qb[0] + dq, q1 = qb[1] + dq;
        const int s0 = (q0 & 7) << 2, s1 = (q1 & 7) << 2;
        const unsigned char* bb = Bb2[u & 1];
#pragma unroll
        for (int c = 0; c < 2; ++c) {
            const int cb = (u & 1) * 2 + c;
            v4i a0 = *(const v4i*)&xs[q0 * 32 + ((cb * 8 + hi4) ^ s0)];
            v4i a1 = *(const v4i*)&xs[q1 * 32 + ((cb * 8 + hi4) ^ s1)];
            const unsigned char* bc = bb + c * 4096;
            v4i b0 = *(const v4i*)(bc + boff[0]);
            v4i b1 = *(const v4i*)(bc + boff[1]);
            v4i b2 = *(const v4i*)(bc + boff[2]);
            v4i b3 = *(const v4i*)(bc + boff[3]);
            acc[0][0] = __builtin_amdgcn_mfma_i32_32x32x32_i8(b0, a0, acc[0][0], 0, 0, 0);
            acc[0][1] = __builtin_amdgcn_mfma_i32_32x32x32_i8(b1, a0, acc[0][1], 0, 0, 0);
            acc[0][2] = __builtin_amdgcn_mfma_i32_32x32x32_i8(b2, a0, acc[0][2], 0, 0, 0);
            acc[0][3] = __builtin_amdgcn_mfma_i32_32x32x32_i8(b3, a0, acc[0][3], 0, 0, 0);
            acc[1][0] = __builtin_amdgcn_mfma_i32_32x32x32_i8(b0, a1, acc[1][0], 0, 0, 0);
            acc[1][1] = __builtin_amdgcn_mfma_i32_32x32x32_i8(b1, a1, acc[1][1], 0, 0, 0);
            acc[1][2] = __builtin_amdgcn_mfma_i32_32x32x32_i8(b2, a1, acc[1][2], 0, 0, 0);
            acc[1][3] = __builtin_amdgcn_mfma_i32_32x32x32_i8(b3, a1, acc[1][3], 0, 0, 0);
        }
        __syncthreads();
    }

    const float zpo = (float)(*zp_out_p);
#pragma unroll
    for (int i = 0; i < 2; ++i) {
        const int px = (wave * 2 + i) * 32 + lane31;
        if (px < ROWS * HW) {
            int* ob = out + n * COUT * NPIX + ho0 * HW + px;
#pragma unroll
            for (int nt = 0; nt < 4; ++nt) {
#pragma unroll
                for (int reg = 0; reg < 16; ++reg) {
                    int co = nt * 32 + (reg & 3) + 8 * (reg >> 2) + hi4;
                    float f = fmaf((float)(acc[i][nt][reg] + bis[co]), scs[co], zpo);
                    f = rintf(f);
                    f = fminf(fmaxf(f, -128.0f), 127.0f);
                    ob[co * NPIX] = (int)f;
                }
            }
        }
    }
}

extern "C" void kernel_launch(void* const* d_in, const int* in_sizes, int n_in,
                              void* d_out, int out_size, void* d_ws, size_t ws_size,
                              hipStream_t stream) {
    const int* x_g      = (const int*)d_in[0];
    const int* w_g      = (const int*)d_in[1];
    const int* bias     = (const int*)d_in[2];
    const float* in_s   = (const float*)d_in[3];
    const float* w_s    = (const float*)d_in[4];
    const float* out_s  = (const float*)d_in[5];
    const int* zp_in_p  = (const int*)d_in[6];
    const int* zp_out_p = (const int*)d_in[7];
    int* outp = (int*)d_out;
    unsigned* wp2 = (unsigned*)d_ws;                           // 147456 B
    unsigned char* xpp = (unsigned char*)d_ws + XP_OFF;        // 27,557,888 B

    pack_w2<<<(36 * 128 * 8 + 255) / 256, 256, 0, stream>>>(w_g, wp2);
    repack_x<<<XP_ROWS, 256, 0, stream>>>(x_g, xpp, zp_in_p);

    const int nblocks = 64 * (HW / ROWS);   // 896
    conv_mfma<<<nblocks, 256, 0, stream>>>(xpp, (const unsigned char*)wp2, bias,
                                           in_s, w_s, out_s, zp_out_p, outp);
}